// Round 9
// baseline (557.375 us; speedup 1.0000x reference)
//
#include <hip/hip_runtime.h>
#include <math.h>

// VQ-VAE forward. MI355X / gfx950. bf16-MFMA everywhere; vq split to 32-row blocks (grid 2048).
// prep -> pack -> conv1(bf16 out) -> conv2+3(MFMA+LDS, enc out) -> vq(MFMA) -> deconv1(MFMA) -> deconv2(MFMA+LDS)
// Workspace (float slots):
//   [0)          h1b bf16 (16,777,216 slots); later g bf16 (33,554,432 slots)
//   [33554432)   enc fp32  4,194,304
//   [37748736)   qdec bf16 (2,097,152 slots)
//   [39845888)   enorm     2,048
//   [39847936)   loss      16
//   [39847952)   w2p  bf16 (262,144 slots)
//   [40110096)   dw1p bf16 (131,072 slots)
//   [40241168)   w3p  bf16 (8,192 slots)
//   [40249360)   dwp  bf16 (32,768 slots)
//   [40282128)   ebp  bf16 (65,536 slots) = bf16(-2*emb)
//   total 40,347,664 floats = 161.4 MB

typedef short s16x8 __attribute__((ext_vector_type(8)));
typedef float f32x4 __attribute__((ext_vector_type(4)));

#define LD4(p) (*(const float4*)(p))

__device__ __forceinline__ float leaky(float v) { return v >= 0.f ? v : 0.01f * v; }
__device__ __forceinline__ unsigned short f2b(float f) {
    union { float f; unsigned u; } v; v.f = f;
    unsigned r = v.u + 0x7fffu + ((v.u >> 16) & 1u);
    return (unsigned short)(r >> 16);
}
__device__ __forceinline__ s16x8 ldz(const unsigned short* p, bool ok) {
    s16x8 z = {0,0,0,0,0,0,0,0};
    return ok ? *(const s16x8*)p : z;
}

// ---------------------------------------------------------------- prep: enorm + ebp(-2e bf16) + loss init
__global__ __launch_bounds__(256) void k_prep(const float* __restrict__ emb,
                                              float* __restrict__ enorm, float* __restrict__ loss,
                                              unsigned short* __restrict__ ebp) {
    int t = blockIdx.x * 256 + threadIdx.x;
    if (t == 0) loss[0] = 0.f;
    if (t < 2048) {
        const float* e = emb + t * 64;
        float s = 0.f;
        #pragma unroll
        for (int h = 0; h < 64; ++h) {
            float ev = e[h];
            s += ev * ev;
            ebp[t * 64 + h] = f2b(-2.f * ev);
        }
        enorm[t] = s;
    }
}

// ---------------------------------------------------------------- pack bf16 MFMA fragments
__global__ __launch_bounds__(256) void k_pack(const float* __restrict__ w2, const float* __restrict__ dw1,
                                              const float* __restrict__ w3, const float* __restrict__ dw2,
                                              unsigned short* __restrict__ w2p, unsigned short* __restrict__ dw1p,
                                              unsigned short* __restrict__ w3p, unsigned short* __restrict__ dwp) {
    int t = blockIdx.x * 256 + threadIdx.x;
    if (t < 524288) {
        int j = t & 7, lane = (t >> 3) & 63, nsg = (t >> 9) & 15, cc = (t >> 13) & 3, tap = t >> 15;
        int c = cc * 32 + ((lane >> 4) << 3) + j;
        int oc = nsg * 16 + (lane & 15);
        w2p[t] = f2b(w2[(tap * 128 + c) * 256 + oc]);
    } else if (t < 786432) {
        int u = t - 524288;
        int j = u & 7, lane = (u >> 3) & 63, nsg = (u >> 9) & 15, cc = (u >> 13) & 1, tap = u >> 14;
        int c = cc * 32 + ((lane >> 4) << 3) + j;
        int oc = nsg * 16 + (lane & 15);
        dw1p[u] = f2b(dw1[(tap * 64 + c) * 256 + oc]);
    } else if (t < 802816) {
        int v = t - 786432;
        int j = v & 7, lane = (v >> 3) & 63, ks = (v >> 9) & 7, wv = v >> 12;
        int c = ks * 32 + ((lane >> 4) << 3) + j;
        int d = wv * 16 + (lane & 15);
        w3p[v] = f2b(w3[c * 64 + d]);
    } else {
        int u2 = t - 802816;  // 65536
        int j = u2 & 7, lane = (u2 >> 3) & 63, ks = (u2 >> 9) & 31, par = u2 >> 14;
        int py = par >> 1, px0 = par & 1;
        int k = ks * 32 + ((lane >> 4) << 3) + j;
        int tap = k >> 8, c = k & 255;
        int ky = py + 2 * (tap >> 1), kx = px0 + 2 * (tap & 1);
        int oc = lane & 15;
        dwp[u2] = (oc < 3) ? f2b(dw2[((ky * 4 + kx) * 256 + c) * 3 + oc]) : (unsigned short)0;
    }
}

// ---------------------------------------------------------------- conv1: x[16,256,256,3] -> h1b bf16[16,128,128,128]
__global__ __launch_bounds__(128) void k_conv1(const float* __restrict__ x, const float* __restrict__ w1,
                                               const float* __restrict__ b1, unsigned short* __restrict__ h1b) {
    __shared__ float smem[120]; // [iy 4][ix 10][c 3]
    int bx = blockIdx.x;
    int xg = bx & 31, y = (bx >> 5) & 127, b = bx >> 12;
    int x0 = xg << 2;
    int tid = threadIdx.x;
    if (tid < 120) {
        int c = tid % 3, sp = tid / 3;
        int iy = sp / 10, ix = sp - iy * 10;
        int gy = 2 * y - 1 + iy, gx = 2 * x0 - 1 + ix;
        float v = 0.f;
        if ((unsigned)gy < 256u && (unsigned)gx < 256u)
            v = x[((b * 256 + gy) * 256 + gx) * 3 + c];
        smem[tid] = v;
    }
    __syncthreads();
    int o = tid;
    float a0 = 0.f, a1 = 0.f, a2 = 0.f, a3 = 0.f;
    #pragma unroll
    for (int ky = 0; ky < 4; ++ky)
        #pragma unroll
        for (int kx = 0; kx < 4; ++kx)
            #pragma unroll
            for (int c = 0; c < 3; ++c) {
                float wv = w1[((ky * 4 + kx) * 3 + c) * 128 + o];
                a0 += smem[(ky * 10 + kx + 0) * 3 + c] * wv;
                a1 += smem[(ky * 10 + kx + 2) * 3 + c] * wv;
                a2 += smem[(ky * 10 + kx + 4) * 3 + c] * wv;
                a3 += smem[(ky * 10 + kx + 6) * 3 + c] * wv;
            }
    float bb = b1[o];
    int ob = ((b * 128 + y) * 128 + x0) * 128 + o;
    h1b[ob]       = f2b(leaky(a0 + bb));
    h1b[ob + 128] = f2b(leaky(a1 + bb));
    h1b[ob + 256] = f2b(leaky(a2 + bb));
    h1b[ob + 384] = f2b(leaky(a3 + bb));
}

// ---------------------------------------------------------------- conv2 MFMA (LDS-staged) + fused conv3
__global__ __launch_bounds__(256) void k_conv2(const unsigned short* __restrict__ h1b,
                                               const unsigned short* __restrict__ w2p,
                                               const float* __restrict__ b2,
                                               const unsigned short* __restrict__ w3p,
                                               const float* __restrict__ b3,
                                               float* __restrict__ enc) {
    __shared__ unsigned short stg[2][132 * 128];   // 67.6 KB; stg[0] reused as h2s (64x256) in epilogue
    int bx = blockIdx.x;
    int swz = (bx & 7) * 128 + (bx >> 3);          // XCD-chunked: contiguous (b,y0) per XCD
    int y0 = swz & 63, b = swz >> 6;
    int tid = threadIdx.x;
    int wv = tid >> 6, lane = tid & 63;
    int lr = lane & 15, lk = lane >> 4;
    f32x4 acc[4][4];
    #pragma unroll
    for (int i = 0; i < 4; ++i)
        #pragma unroll
        for (int j = 0; j < 4; ++j) acc[i][j] = (f32x4){0.f, 0.f, 0.f, 0.f};

    const unsigned short* hbase = h1b + (size_t)b * (128 * 128 * 128);

    // ---- stage row 0 into buf0
    {
        int gy = 2 * y0 - 1;
        bool ok = (unsigned)gy < 128u;
        const unsigned short* rowp = hbase + gy * (128 * 128);
        #pragma unroll
        for (int it = 0; it < 8; ++it) {
            int e = it * 256 + tid;
            int cg = e & 15, px = e >> 4;
            int s = px + 1;
            s16x8 v = ldz(rowp + px * 128 + cg * 8, ok);
            *(s16x8*)(stg[0] + s * 128 + (((cg ^ ((s >> 1) & 15))) << 3)) = v;
        }
        if (tid < 32) {
            int cg = tid & 15, s = (tid >> 4) ? 129 : 0;
            s16x8 z = {0,0,0,0,0,0,0,0};
            *(s16x8*)(stg[0] + s * 128 + (((cg ^ ((s >> 1) & 15))) << 3)) = z;
        }
    }
    __syncthreads();

    #pragma unroll
    for (int ky = 0; ky < 4; ++ky) {
        int bufi = ky & 1;
        s16x8 pre[8];
        bool nok = false;
        const unsigned short* nrowp = nullptr;
        if (ky < 3) {
            int gy = 2 * y0 + ky;
            nok = (unsigned)gy < 128u;
            nrowp = hbase + gy * (128 * 128);
            #pragma unroll
            for (int it = 0; it < 8; ++it) {
                int e = it * 256 + tid;
                int cg = e & 15, px = e >> 4;
                pre[it] = ldz(nrowp + px * 128 + cg * 8, nok);
            }
        }
        #pragma unroll
        for (int kx = 0; kx < 4; ++kx) {
            int tap = ky * 4 + kx;
            #pragma unroll
            for (int cc = 0; cc < 4; ++cc) {
                s16x8 aF[4];
                #pragma unroll
                for (int ms = 0; ms < 4; ++ms) {
                    int s = 2 * lr + kx + ms * 32;
                    aF[ms] = *(const s16x8*)(stg[bufi] + s * 128 + ((((cc * 4 + lk) ^ ((s >> 1) & 15))) << 3));
                }
                const unsigned short* wp = w2p + (((tap * 4 + cc) * 16 + wv * 4) * 64 + lane) * 8;
                s16x8 bF[4];
                #pragma unroll
                for (int ns = 0; ns < 4; ++ns) bF[ns] = *(const s16x8*)(wp + ns * 512);
                #pragma unroll
                for (int ms = 0; ms < 4; ++ms)
                    #pragma unroll
                    for (int ns = 0; ns < 4; ++ns)
                        acc[ms][ns] = __builtin_amdgcn_mfma_f32_16x16x32_bf16(aF[ms], bF[ns], acc[ms][ns], 0, 0, 0);
            }
        }
        if (ky < 3) {
            #pragma unroll
            for (int it = 0; it < 8; ++it) {
                int e = it * 256 + tid;
                int cg = e & 15, px = e >> 4;
                int s = px + 1;
                *(s16x8*)(stg[bufi ^ 1] + s * 128 + (((cg ^ ((s >> 1) & 15))) << 3)) = pre[it];
            }
            if (tid < 32) {
                int cg = tid & 15, s = (tid >> 4) ? 129 : 0;
                s16x8 z = {0,0,0,0,0,0,0,0};
                *(s16x8*)(stg[bufi ^ 1] + s * 128 + (((cg ^ ((s >> 1) & 15))) << 3)) = z;
            }
            __syncthreads();
        }
    }

    // epilogue 1: bias + leaky -> bf16 LDS tile (h2s aliases stg[0])
    unsigned short* h2s = stg[0];
    int ocb = wv * 64;
    #pragma unroll
    for (int ns = 0; ns < 4; ++ns) {
        int c = ocb + ns * 16 + lr;
        float bb = b2[c];
        int cg = c >> 3, cj = c & 7;
        #pragma unroll
        for (int ms = 0; ms < 4; ++ms)
            #pragma unroll
            for (int r = 0; r < 4; ++r) {
                int px = ms * 16 + lk * 4 + r;
                h2s[px * 256 + ((cg ^ (px & 31)) << 3) + cj] = f2b(leaky(acc[ms][ns][r] + bb));
            }
    }
    __syncthreads();
    // conv3: 64px x 64d, K=256
    f32x4 a3[4];
    #pragma unroll
    for (int i = 0; i < 4; ++i) a3[i] = (f32x4){0.f, 0.f, 0.f, 0.f};
    #pragma unroll
    for (int ks = 0; ks < 8; ++ks) {
        s16x8 bF = *(const s16x8*)(w3p + ((wv * 8 + ks) * 64 + lane) * 8);
        int cg = ks * 4 + lk;
        #pragma unroll
        for (int ms = 0; ms < 4; ++ms) {
            int px = lr + ms * 16;
            s16x8 aF = *(const s16x8*)(h2s + px * 256 + ((cg ^ (px & 31)) << 3));
            a3[ms] = __builtin_amdgcn_mfma_f32_16x16x32_bf16(aF, bF, a3[ms], 0, 0, 0);
        }
    }
    float bb3 = b3[wv * 16 + lr];
    float* outp = enc + ((size_t)(b * 64 + y0)) * 64 * 64;
    #pragma unroll
    for (int ms = 0; ms < 4; ++ms)
        #pragma unroll
        for (int r = 0; r < 4; ++r) {
            int px = ms * 16 + lk * 4 + r;
            outp[px * 64 + wv * 16 + lr] = a3[ms][r] + bb3;
        }
}

// ---------------------------------------------------------------- fused VQ via MFMA: 32-row blocks (grid 2048)
// Block rb: half = rb&1 (c range), w = (rb>>1)&63, b = rb>>7. Wave wv covers codes [wv*512, wv*512+512).
__global__ __launch_bounds__(256) void k_vq(const float* __restrict__ enc, const unsigned short* __restrict__ ebp,
                                            const float* __restrict__ emb, const float* __restrict__ enorm,
                                            unsigned short* __restrict__ qdec, float* __restrict__ loss) {
    __shared__ unsigned short f_sw[32 * 64];  // [row][h swizzled] bf16, 4 KB
    __shared__ float en_sh[2048];             // 8 KB
    __shared__ float red_s[4 * 32];
    __shared__ int   red_k[4 * 32];
    __shared__ int   bk_sh[32];

    int rb = blockIdx.x;
    int half = rb & 1, w = (rb >> 1) & 63, b = rb >> 7;
    int tid = threadIdx.x;
    int row0 = tid & 31, hgx = tid >> 5;     // 32 rows x 8 h-slots

    const float* encb = enc + b * 262144 + w * 64 + half * 32;   // [h stride 4096][row]
    #pragma unroll
    for (int hp = 0; hp < 8; ++hp) {
        int h = hp * 8 + hgx;
        f_sw[row0 * 64 + ((((h >> 3) ^ (row0 & 7)) << 3) | (h & 7))] = f2b(encb[h * 4096 + row0]);
    }
    #pragma unroll
    for (int j = 0; j < 8; ++j) {
        int e = j * 256 + tid;
        en_sh[e] = enorm[e];
    }
    __syncthreads();

    int wv = tid >> 6, lane = tid & 63, lr = lane & 15, lk = lane >> 4;
    s16x8 aF[2][2];
    #pragma unroll
    for (int ms = 0; ms < 2; ++ms)
        #pragma unroll
        for (int ks = 0; ks < 2; ++ks) {
            int row = ms * 16 + lr;
            int grp = ((ks << 2) | lk) ^ (row & 7);
            aF[ms][ks] = *(const s16x8*)(f_sw + row * 64 + (grp << 3));
        }

    float bs[2][4]; int bkr[2][4];
    #pragma unroll
    for (int ms = 0; ms < 2; ++ms)
        #pragma unroll
        for (int r = 0; r < 4; ++r) { bs[ms][r] = 3.4e38f; bkr[ms][r] = 0; }

    const unsigned short* ebw = ebp + (size_t)(wv * 512) * 64;
    #pragma unroll 1
    for (int j = 0; j < 32; ++j) {
        const unsigned short* ep = ebw + (j * 16 + lr) * 64 + lk * 8;
        s16x8 bF0 = *(const s16x8*)(ep);
        s16x8 bF1 = *(const s16x8*)(ep + 32);
        int kg = wv * 512 + j * 16 + lr;
        float en = en_sh[kg];
        #pragma unroll
        for (int ms = 0; ms < 2; ++ms) {
            f32x4 d = {en, en, en, en};
            d = __builtin_amdgcn_mfma_f32_16x16x32_bf16(aF[ms][0], bF0, d, 0, 0, 0);
            d = __builtin_amdgcn_mfma_f32_16x16x32_bf16(aF[ms][1], bF1, d, 0, 0, 0);
            #pragma unroll
            for (int r = 0; r < 4; ++r) {
                if (d[r] < bs[ms][r]) { bs[ms][r] = d[r]; bkr[ms][r] = kg; }
            }
        }
    }

    // butterfly over the 16 code-residues (lr bits)
    #pragma unroll
    for (int off = 1; off <= 8; off <<= 1) {
        #pragma unroll
        for (int ms = 0; ms < 2; ++ms)
            #pragma unroll
            for (int r = 0; r < 4; ++r) {
                float os = __shfl_xor(bs[ms][r], off, 64);
                int ok = __shfl_xor(bkr[ms][r], off, 64);
                if (os < bs[ms][r] || (os == bs[ms][r] && ok < bkr[ms][r])) {
                    bs[ms][r] = os; bkr[ms][r] = ok;
                }
            }
    }
    if (lr == 0) {
        #pragma unroll
        for (int ms = 0; ms < 2; ++ms)
            #pragma unroll
            for (int r = 0; r < 4; ++r) {
                int row = ms * 16 + lk * 4 + r;
                red_s[wv * 32 + row] = bs[ms][r];
                red_k[wv * 32 + row] = bkr[ms][r];
            }
    }
    __syncthreads();
    if (tid < 32) {
        float s0 = red_s[tid]; int k0 = red_k[tid];
        #pragma unroll
        for (int v = 1; v < 4; ++v) {   // ascending wave = ascending code range -> first-min
            float s = red_s[v * 32 + tid]; int k = red_k[v * 32 + tid];
            if (s < s0 || (s == s0 && k < k0)) { s0 = s; k0 = k; }
        }
        bk_sh[tid] = k0;
    }
    __syncthreads();

    // epilogue: loss (fp32 enc) + quant scatter
    int bcode = bk_sh[row0];
    const float* ev = emb + bcode * 64;
    unsigned short* qd = qdec + b * 262144 + w * 64 + half * 32 + row0;
    float ls = 0.f;
    #pragma unroll
    for (int hp = 0; hp < 8; ++hp) {
        int h = hp * 8 + hgx;
        float e = ev[h];
        float f = encb[h * 4096 + row0];
        float d = e - f;
        ls += d * d;
        qd[h * 4096] = f2b(e);
    }
    #pragma unroll
    for (int off = 32; off; off >>= 1) ls += __shfl_xor(ls, off, 64);
    if ((tid & 63) == 0) atomicAdd(loss, ls);
}

// ---------------------------------------------------------------- deconv1 MFMA: qdec bf16 -> g bf16[16,128,128,256]
__global__ __launch_bounds__(256) void k_deconv1(const unsigned short* __restrict__ qdec,
                                                 const unsigned short* __restrict__ dw1p,
                                                 const float* __restrict__ db1, unsigned short* __restrict__ g) {
    int bx = blockIdx.x;
    int parx = bx & 1, y = (bx >> 1) & 127, b = bx >> 8;
    int pary = y & 1;
    int h0 = (y - 2 + pary) >> 1;
    int tid = threadIdx.x;
    int wv = tid >> 6, lane = tid & 63;
    int lr = lane & 15, lk = lane >> 4;
    f32x4 acc[4][4];
    #pragma unroll
    for (int i = 0; i < 4; ++i)
        #pragma unroll
        for (int j = 0; j < 4; ++j) acc[i][j] = (f32x4){0.f, 0.f, 0.f, 0.f};

    const unsigned short* qb = qdec + (size_t)b * (64 * 64 * 64);
    #pragma unroll
    for (int tky = 0; tky < 2; ++tky) {
        int h = h0 + tky;
        bool hok = (unsigned)h < 64u;
        const unsigned short* rowp = qb + h * (64 * 64);
        #pragma unroll
        for (int tkx = 0; tkx < 2; ++tkx) {
            int tap = (pary + 2 * tky) * 4 + parx + 2 * tkx;
            int wbase = lr + parx + tkx - 1;
            #pragma unroll
            for (int cc = 0; cc < 2; ++cc) {
                int c0 = cc * 32 + lk * 8;
                s16x8 aF[4];
                #pragma unroll
                for (int ms = 0; ms < 4; ++ms) {
                    int w = wbase + ms * 16;
                    aF[ms] = ldz(rowp + w * 64 + c0, hok && (unsigned)w < 64u);
                }
                const unsigned short* wp = dw1p + (((tap * 2 + cc) * 16 + wv * 4) * 64 + lane) * 8;
                s16x8 bF[4];
                #pragma unroll
                for (int ns = 0; ns < 4; ++ns) bF[ns] = *(const s16x8*)(wp + ns * 512);
                #pragma unroll
                for (int ms = 0; ms < 4; ++ms)
                    #pragma unroll
                    for (int ns = 0; ns < 4; ++ns)
                        acc[ms][ns] = __builtin_amdgcn_mfma_f32_16x16x32_bf16(aF[ms], bF[ns], acc[ms][ns], 0, 0, 0);
            }
        }
    }
    int ocb = wv * 64;
    unsigned short* gp = g + ((size_t)(b * 128 + y)) * 128 * 256;
    #pragma unroll
    for (int ns = 0; ns < 4; ++ns) {
        float bb = db1[ocb + ns * 16 + lr];
        #pragma unroll
        for (int ms = 0; ms < 4; ++ms)
            #pragma unroll
            for (int r = 0; r < 4; ++r) {
                int u = ms * 16 + lk * 4 + r;
                int xo = 2 * u + parx;
                gp[xo * 256 + ocb + ns * 16 + lr] = f2b(leaky(acc[ms][ns][r] + bb));
            }
    }
}

// ---------------------------------------------------------------- deconv2 MFMA, LDS-staged: g bf16 -> recon fp32, tanh
__global__ __launch_bounds__(256) void k_deconv2(const unsigned short* __restrict__ g,
                                                 const unsigned short* __restrict__ dwp,
                                                 const float* __restrict__ db2, float* __restrict__ out,
                                                 const float* __restrict__ loss) {
    __shared__ unsigned short gs[2][128][128];
    int bx = blockIdx.x;
    int swz = (bx % 8) * 258 + bx / 8;        // 2064 blocks; XCD-chunked
    int b = swz / 129, m = swz % 129;
    int tid = threadIdx.x;
    int wv = tid >> 6, lane = tid & 63;
    int lr = lane & 15, lk = lane >> 4;
    int yi = wv >> 1, px0 = wv & 1;
    int y = 2 * m - 1 + yi;
    int py = yi ^ 1;

    f32x4 acc[8];
    #pragma unroll
    for (int i = 0; i < 8; ++i) acc[i] = (f32x4){0.f, 0.f, 0.f, 0.f};

    const unsigned short* gb = g + (size_t)b * (128 * 128 * 256);
    const unsigned short* dwb = dwp + (size_t)(py * 2 + px0) * 32 * 512;

    #pragma unroll 1
    for (int cc = 0; cc < 2; ++cc) {
        __syncthreads();
        #pragma unroll
        for (int i = 0; i < 16; ++i) {
            int ch = i * 256 + tid;             // 0..4095
            int cg = ch & 15;
            int w  = (ch >> 4) & 127;
            int tky = ch >> 11;
            int h = m - 1 + tky;
            s16x8 v = {0,0,0,0,0,0,0,0};
            if ((unsigned)h < 128u)
                v = *(const s16x8*)(gb + h * (128 * 256) + w * 256 + cc * 128 + cg * 8);
            *(s16x8*)(&gs[tky][w][(cg ^ (w & 15)) << 3]) = v;
        }
        __syncthreads();
        #pragma unroll
        for (int tky = 0; tky < 2; ++tky) {
            #pragma unroll
            for (int tkx = 0; tkx < 2; ++tkx) {
                int tap = tky * 2 + tkx;
                int wofs = px0 - 1 + tkx;
                #pragma unroll
                for (int k8 = 0; k8 < 4; ++k8) {
                    int ks = tap * 8 + cc * 4 + k8;
                    s16x8 bF = *(const s16x8*)(dwb + (ks * 64 + lane) * 8);
                    int cg = k8 * 4 + lk;
                    #pragma unroll
                    for (int ms = 0; ms < 8; ++ms) {
                        int w = ms * 16 + lr + wofs;
                        s16x8 aF = {0,0,0,0,0,0,0,0};
                        if ((unsigned)w < 128u)
                            aF = *(const s16x8*)(&gs[tky][w][(cg ^ (w & 15)) << 3]);
                        acc[ms] = __builtin_amdgcn_mfma_f32_16x16x32_bf16(aF, bF, acc[ms], 0, 0, 0);
                    }
                }
            }
        }
    }
    if ((unsigned)y < 256u && lr < 3) {
        float bb = db2[lr];
        #pragma unroll
        for (int ms = 0; ms < 8; ++ms)
            #pragma unroll
            for (int r = 0; r < 4; ++r) {
                int n = ms * 16 + lk * 4 + r;
                int x = 2 * n + px0;
                out[((size_t)b * 65536 + y * 256 + x) * 3 + lr] = tanhf(acc[ms][r] + bb);
            }
    }
    if (bx == 0 && tid == 0)
        out[3145728] = loss[0] * (1.25f / 4194304.f);
}

// ---------------------------------------------------------------- launch
extern "C" void kernel_launch(void* const* d_in, const int* in_sizes, int n_in,
                              void* d_out, int out_size, void* d_ws, size_t ws_size,
                              hipStream_t stream) {
    const float* x   = (const float*)d_in[0];
    const float* emb = (const float*)d_in[1];
    const float* w1  = (const float*)d_in[2];
    const float* b1  = (const float*)d_in[3];
    const float* w2  = (const float*)d_in[4];
    const float* b2  = (const float*)d_in[5];
    const float* w3  = (const float*)d_in[6];
    const float* b3  = (const float*)d_in[7];
    const float* dw1 = (const float*)d_in[8];
    const float* db1 = (const float*)d_in[9];
    const float* dw2 = (const float*)d_in[10];
    const float* db2 = (const float*)d_in[11];
    float* out = (float*)d_out;
    float* ws  = (float*)d_ws;

    if (ws_size < (size_t)40347664 * 4) return;

    unsigned short* h1b  = (unsigned short*)ws;            // bf16, later overlapped by g
    unsigned short* g    = (unsigned short*)ws;            // bf16 [16,128,128,256]
    float* enc   = ws + 33554432;
    unsigned short* qdec = (unsigned short*)(ws + 37748736);
    float* enorm = ws + 39845888;
    float* loss  = ws + 39847936;
    unsigned short* w2p  = (unsigned short*)(ws + 39847952);
    unsigned short* dw1p = (unsigned short*)(ws + 40110096);
    unsigned short* w3p  = (unsigned short*)(ws + 40241168);
    unsigned short* dwp  = (unsigned short*)(ws + 40249360);
    unsigned short* ebp  = (unsigned short*)(ws + 40282128);

    k_prep   <<<8,     256, 0, stream>>>(emb, enorm, loss, ebp);
    k_pack   <<<3392,  256, 0, stream>>>(w2, dw1, w3, dw2, w2p, dw1p, w3p, dwp);
    k_conv1  <<<65536, 128, 0, stream>>>(x, w1, b1, h1b);
    k_conv2  <<<1024,  256, 0, stream>>>(h1b, w2p, b2, w3p, b3, enc);
    k_vq     <<<2048,  256, 0, stream>>>(enc, ebp, emb, enorm, qdec, loss);
    k_deconv1<<<4096,  256, 0, stream>>>(qdec, dw1p, db1, g);
    k_deconv2<<<2064,  256, 0, stream>>>(g, dwp, db2, out, loss);
}

// Round 10
// 461.697 us; speedup vs baseline: 1.2072x; 1.2072x over previous
//
#include <hip/hip_runtime.h>
#include <math.h>

// VQ-VAE forward. MI355X / gfx950. bf16-MFMA everywhere.
// prep -> pack -> conv1 -> conv2+3(MFMA+LDS) -> vq(MFMA, pipelined, no atomics) -> losssum -> deconv1 -> deconv2
// Workspace (float slots):
//   [0)          h1b bf16 (16,777,216 slots); later g bf16 (33,554,432 slots)
//   [33554432)   enc fp32  4,194,304
//   [37748736)   qdec bf16 (2,097,152 slots)
//   [39845888)   enorm     2,048
//   [39847936)   loss      16
//   [39847952)   w2p  bf16 (262,144 slots)
//   [40110096)   dw1p bf16 (131,072 slots)
//   [40241168)   w3p  bf16 (8,192 slots)
//   [40249360)   dwp  bf16 (32,768 slots)
//   [40282128)   ebp  bf16 (65,536 slots) = bf16(-2*emb)
//   [40347664)   lossp 1,024 (per-block loss partials)
//   total 40,348,688 floats = 161.4 MB

typedef short s16x8 __attribute__((ext_vector_type(8)));
typedef float f32x4 __attribute__((ext_vector_type(4)));

#define LD4(p) (*(const float4*)(p))

__device__ __forceinline__ float leaky(float v) { return v >= 0.f ? v : 0.01f * v; }
__device__ __forceinline__ unsigned short f2b(float f) {
    union { float f; unsigned u; } v; v.f = f;
    unsigned r = v.u + 0x7fffu + ((v.u >> 16) & 1u);
    return (unsigned short)(r >> 16);
}
__device__ __forceinline__ s16x8 ldz(const unsigned short* p, bool ok) {
    s16x8 z = {0,0,0,0,0,0,0,0};
    return ok ? *(const s16x8*)p : z;
}

// ---------------------------------------------------------------- prep: enorm + ebp(-2e bf16) + loss init
__global__ __launch_bounds__(256) void k_prep(const float* __restrict__ emb,
                                              float* __restrict__ enorm, float* __restrict__ loss,
                                              unsigned short* __restrict__ ebp) {
    int t = blockIdx.x * 256 + threadIdx.x;
    if (t == 0) loss[0] = 0.f;
    if (t < 2048) {
        const float* e = emb + t * 64;
        float s = 0.f;
        #pragma unroll
        for (int h = 0; h < 64; ++h) {
            float ev = e[h];
            s += ev * ev;
            ebp[t * 64 + h] = f2b(-2.f * ev);
        }
        enorm[t] = s;
    }
}

// ---------------------------------------------------------------- pack bf16 MFMA fragments
__global__ __launch_bounds__(256) void k_pack(const float* __restrict__ w2, const float* __restrict__ dw1,
                                              const float* __restrict__ w3, const float* __restrict__ dw2,
                                              unsigned short* __restrict__ w2p, unsigned short* __restrict__ dw1p,
                                              unsigned short* __restrict__ w3p, unsigned short* __restrict__ dwp) {
    int t = blockIdx.x * 256 + threadIdx.x;
    if (t < 524288) {
        int j = t & 7, lane = (t >> 3) & 63, nsg = (t >> 9) & 15, cc = (t >> 13) & 3, tap = t >> 15;
        int c = cc * 32 + ((lane >> 4) << 3) + j;
        int oc = nsg * 16 + (lane & 15);
        w2p[t] = f2b(w2[(tap * 128 + c) * 256 + oc]);
    } else if (t < 786432) {
        int u = t - 524288;
        int j = u & 7, lane = (u >> 3) & 63, nsg = (u >> 9) & 15, cc = (u >> 13) & 1, tap = u >> 14;
        int c = cc * 32 + ((lane >> 4) << 3) + j;
        int oc = nsg * 16 + (lane & 15);
        dw1p[u] = f2b(dw1[(tap * 64 + c) * 256 + oc]);
    } else if (t < 802816) {
        int v = t - 786432;
        int j = v & 7, lane = (v >> 3) & 63, ks = (v >> 9) & 7, wv = v >> 12;
        int c = ks * 32 + ((lane >> 4) << 3) + j;
        int d = wv * 16 + (lane & 15);
        w3p[v] = f2b(w3[c * 64 + d]);
    } else {
        int u2 = t - 802816;  // 65536
        int j = u2 & 7, lane = (u2 >> 3) & 63, ks = (u2 >> 9) & 31, par = u2 >> 14;
        int py = par >> 1, px0 = par & 1;
        int k = ks * 32 + ((lane >> 4) << 3) + j;
        int tap = k >> 8, c = k & 255;
        int ky = py + 2 * (tap >> 1), kx = px0 + 2 * (tap & 1);
        int oc = lane & 15;
        dwp[u2] = (oc < 3) ? f2b(dw2[((ky * 4 + kx) * 256 + c) * 3 + oc]) : (unsigned short)0;
    }
}

// ---------------------------------------------------------------- conv1: x[16,256,256,3] -> h1b bf16[16,128,128,128]
__global__ __launch_bounds__(128) void k_conv1(const float* __restrict__ x, const float* __restrict__ w1,
                                               const float* __restrict__ b1, unsigned short* __restrict__ h1b) {
    __shared__ float smem[120]; // [iy 4][ix 10][c 3]
    int bx = blockIdx.x;
    int xg = bx & 31, y = (bx >> 5) & 127, b = bx >> 12;
    int x0 = xg << 2;
    int tid = threadIdx.x;
    if (tid < 120) {
        int c = tid % 3, sp = tid / 3;
        int iy = sp / 10, ix = sp - iy * 10;
        int gy = 2 * y - 1 + iy, gx = 2 * x0 - 1 + ix;
        float v = 0.f;
        if ((unsigned)gy < 256u && (unsigned)gx < 256u)
            v = x[((b * 256 + gy) * 256 + gx) * 3 + c];
        smem[tid] = v;
    }
    __syncthreads();
    int o = tid;
    float a0 = 0.f, a1 = 0.f, a2 = 0.f, a3 = 0.f;
    #pragma unroll
    for (int ky = 0; ky < 4; ++ky)
        #pragma unroll
        for (int kx = 0; kx < 4; ++kx)
            #pragma unroll
            for (int c = 0; c < 3; ++c) {
                float wv = w1[((ky * 4 + kx) * 3 + c) * 128 + o];
                a0 += smem[(ky * 10 + kx + 0) * 3 + c] * wv;
                a1 += smem[(ky * 10 + kx + 2) * 3 + c] * wv;
                a2 += smem[(ky * 10 + kx + 4) * 3 + c] * wv;
                a3 += smem[(ky * 10 + kx + 6) * 3 + c] * wv;
            }
    float bb = b1[o];
    int ob = ((b * 128 + y) * 128 + x0) * 128 + o;
    h1b[ob]       = f2b(leaky(a0 + bb));
    h1b[ob + 128] = f2b(leaky(a1 + bb));
    h1b[ob + 256] = f2b(leaky(a2 + bb));
    h1b[ob + 384] = f2b(leaky(a3 + bb));
}

// ---------------------------------------------------------------- conv2 MFMA (LDS-staged) + fused conv3
__global__ __launch_bounds__(256) void k_conv2(const unsigned short* __restrict__ h1b,
                                               const unsigned short* __restrict__ w2p,
                                               const float* __restrict__ b2,
                                               const unsigned short* __restrict__ w3p,
                                               const float* __restrict__ b3,
                                               float* __restrict__ enc) {
    __shared__ unsigned short stg[2][132 * 128];   // 67.6 KB; stg[0] reused as h2s (64x256) in epilogue
    int bx = blockIdx.x;
    int swz = (bx & 7) * 128 + (bx >> 3);          // XCD-chunked: contiguous (b,y0) per XCD
    int y0 = swz & 63, b = swz >> 6;
    int tid = threadIdx.x;
    int wv = tid >> 6, lane = tid & 63;
    int lr = lane & 15, lk = lane >> 4;
    f32x4 acc[4][4];
    #pragma unroll
    for (int i = 0; i < 4; ++i)
        #pragma unroll
        for (int j = 0; j < 4; ++j) acc[i][j] = (f32x4){0.f, 0.f, 0.f, 0.f};

    const unsigned short* hbase = h1b + (size_t)b * (128 * 128 * 128);

    {
        int gy = 2 * y0 - 1;
        bool ok = (unsigned)gy < 128u;
        const unsigned short* rowp = hbase + gy * (128 * 128);
        #pragma unroll
        for (int it = 0; it < 8; ++it) {
            int e = it * 256 + tid;
            int cg = e & 15, px = e >> 4;
            int s = px + 1;
            s16x8 v = ldz(rowp + px * 128 + cg * 8, ok);
            *(s16x8*)(stg[0] + s * 128 + (((cg ^ ((s >> 1) & 15))) << 3)) = v;
        }
        if (tid < 32) {
            int cg = tid & 15, s = (tid >> 4) ? 129 : 0;
            s16x8 z = {0,0,0,0,0,0,0,0};
            *(s16x8*)(stg[0] + s * 128 + (((cg ^ ((s >> 1) & 15))) << 3)) = z;
        }
    }
    __syncthreads();

    #pragma unroll
    for (int ky = 0; ky < 4; ++ky) {
        int bufi = ky & 1;
        s16x8 pre[8];
        bool nok = false;
        const unsigned short* nrowp = nullptr;
        if (ky < 3) {
            int gy = 2 * y0 + ky;
            nok = (unsigned)gy < 128u;
            nrowp = hbase + gy * (128 * 128);
            #pragma unroll
            for (int it = 0; it < 8; ++it) {
                int e = it * 256 + tid;
                int cg = e & 15, px = e >> 4;
                pre[it] = ldz(nrowp + px * 128 + cg * 8, nok);
            }
        }
        #pragma unroll
        for (int kx = 0; kx < 4; ++kx) {
            int tap = ky * 4 + kx;
            #pragma unroll
            for (int cc = 0; cc < 4; ++cc) {
                s16x8 aF[4];
                #pragma unroll
                for (int ms = 0; ms < 4; ++ms) {
                    int s = 2 * lr + kx + ms * 32;
                    aF[ms] = *(const s16x8*)(stg[bufi] + s * 128 + ((((cc * 4 + lk) ^ ((s >> 1) & 15))) << 3));
                }
                const unsigned short* wp = w2p + (((tap * 4 + cc) * 16 + wv * 4) * 64 + lane) * 8;
                s16x8 bF[4];
                #pragma unroll
                for (int ns = 0; ns < 4; ++ns) bF[ns] = *(const s16x8*)(wp + ns * 512);
                #pragma unroll
                for (int ms = 0; ms < 4; ++ms)
                    #pragma unroll
                    for (int ns = 0; ns < 4; ++ns)
                        acc[ms][ns] = __builtin_amdgcn_mfma_f32_16x16x32_bf16(aF[ms], bF[ns], acc[ms][ns], 0, 0, 0);
            }
        }
        if (ky < 3) {
            #pragma unroll
            for (int it = 0; it < 8; ++it) {
                int e = it * 256 + tid;
                int cg = e & 15, px = e >> 4;
                int s = px + 1;
                *(s16x8*)(stg[bufi ^ 1] + s * 128 + (((cg ^ ((s >> 1) & 15))) << 3)) = pre[it];
            }
            if (tid < 32) {
                int cg = tid & 15, s = (tid >> 4) ? 129 : 0;
                s16x8 z = {0,0,0,0,0,0,0,0};
                *(s16x8*)(stg[bufi ^ 1] + s * 128 + (((cg ^ ((s >> 1) & 15))) << 3)) = z;
            }
            __syncthreads();
        }
    }

    unsigned short* h2s = stg[0];
    int ocb = wv * 64;
    #pragma unroll
    for (int ns = 0; ns < 4; ++ns) {
        int c = ocb + ns * 16 + lr;
        float bb = b2[c];
        int cg = c >> 3, cj = c & 7;
        #pragma unroll
        for (int ms = 0; ms < 4; ++ms)
            #pragma unroll
            for (int r = 0; r < 4; ++r) {
                int px = ms * 16 + lk * 4 + r;
                h2s[px * 256 + ((cg ^ (px & 31)) << 3) + cj] = f2b(leaky(acc[ms][ns][r] + bb));
            }
    }
    __syncthreads();
    f32x4 a3[4];
    #pragma unroll
    for (int i = 0; i < 4; ++i) a3[i] = (f32x4){0.f, 0.f, 0.f, 0.f};
    #pragma unroll
    for (int ks = 0; ks < 8; ++ks) {
        s16x8 bF = *(const s16x8*)(w3p + ((wv * 8 + ks) * 64 + lane) * 8);
        int cg = ks * 4 + lk;
        #pragma unroll
        for (int ms = 0; ms < 4; ++ms) {
            int px = lr + ms * 16;
            s16x8 aF = *(const s16x8*)(h2s + px * 256 + ((cg ^ (px & 31)) << 3));
            a3[ms] = __builtin_amdgcn_mfma_f32_16x16x32_bf16(aF, bF, a3[ms], 0, 0, 0);
        }
    }
    float bb3 = b3[wv * 16 + lr];
    float* outp = enc + ((size_t)(b * 64 + y0)) * 64 * 64;
    #pragma unroll
    for (int ms = 0; ms < 4; ++ms)
        #pragma unroll
        for (int r = 0; r < 4; ++r) {
            int px = ms * 16 + lk * 4 + r;
            outp[px * 64 + wv * 16 + lr] = a3[ms][r] + bb3;
        }
}

// ---------------------------------------------------------------- fused VQ via MFMA: 64-row blocks, pipelined, no atomics
__global__ __launch_bounds__(256) void k_vq(const float* __restrict__ enc, const unsigned short* __restrict__ ebp,
                                            const float* __restrict__ emb, const float* __restrict__ enorm,
                                            unsigned short* __restrict__ qdec, float* __restrict__ lossp) {
    __shared__ unsigned short f_sw[64 * 64];  // [row c][h], XOR-swizzled 8-elem groups (8 KB)
    __shared__ float en_sh[2048];             // 8 KB
    __shared__ float red_s[4 * 64];
    __shared__ int   red_k[4 * 64];
    __shared__ int   bk_sh[64];
    __shared__ float wls[4];

    int rb = blockIdx.x;
    int b = rb >> 6, w = rb & 63;
    int tid = threadIdx.x;
    int cl = tid & 63, hg = tid >> 6;

    const float* encb = enc + b * 262144 + w * 64;
    #pragma unroll
    for (int hp = 0; hp < 16; ++hp) {
        int h = hp * 4 + hg;
        f_sw[cl * 64 + ((((h >> 3) ^ (cl & 7)) << 3) | (h & 7))] = f2b(encb[h * 4096 + cl]);
    }
    #pragma unroll
    for (int j = 0; j < 8; ++j) {
        int e = j * 256 + tid;
        en_sh[e] = enorm[e];
    }
    __syncthreads();

    int wv = tid >> 6, lane = tid & 63, lr = lane & 15, lk = lane >> 4;
    s16x8 aF[4][2];
    #pragma unroll
    for (int ms = 0; ms < 4; ++ms)
        #pragma unroll
        for (int ks = 0; ks < 2; ++ks) {
            int row = ms * 16 + lr;
            int grp = ((ks << 2) | lk) ^ (row & 7);
            aF[ms][ks] = *(const s16x8*)(f_sw + row * 64 + (grp << 3));
        }

    float bs[4][4]; int bkr[4][4];
    #pragma unroll
    for (int ms = 0; ms < 4; ++ms)
        #pragma unroll
        for (int r = 0; r < 4; ++r) { bs[ms][r] = 3.4e38f; bkr[ms][r] = 0; }

    const unsigned short* ebw = ebp + (size_t)(wv * 512) * 64;
    // software pipeline: prefetch next j's B-fragments + enorm while computing current
    const unsigned short* ep0 = ebw + lr * 64 + lk * 8;
    s16x8 c0 = *(const s16x8*)(ep0);
    s16x8 c1 = *(const s16x8*)(ep0 + 32);
    float enc_c = en_sh[wv * 512 + lr];
    #pragma unroll 1
    for (int j = 0; j < 32; ++j) {
        s16x8 n0, n1; float en_n;
        if (j < 31) {
            const unsigned short* np = ebw + ((j + 1) * 16 + lr) * 64 + lk * 8;
            n0 = *(const s16x8*)(np);
            n1 = *(const s16x8*)(np + 32);
            en_n = en_sh[wv * 512 + (j + 1) * 16 + lr];
        }
        int kgc = wv * 512 + j * 16 + lr;
        #pragma unroll
        for (int ms = 0; ms < 4; ++ms) {
            f32x4 d = {enc_c, enc_c, enc_c, enc_c};
            d = __builtin_amdgcn_mfma_f32_16x16x32_bf16(aF[ms][0], c0, d, 0, 0, 0);
            d = __builtin_amdgcn_mfma_f32_16x16x32_bf16(aF[ms][1], c1, d, 0, 0, 0);
            #pragma unroll
            for (int r = 0; r < 4; ++r) {
                if (d[r] < bs[ms][r]) { bs[ms][r] = d[r]; bkr[ms][r] = kgc; }
            }
        }
        if (j < 31) { c0 = n0; c1 = n1; enc_c = en_n; }
    }

    // butterfly over the 16 code-residues
    #pragma unroll
    for (int off = 1; off <= 8; off <<= 1) {
        #pragma unroll
        for (int ms = 0; ms < 4; ++ms)
            #pragma unroll
            for (int r = 0; r < 4; ++r) {
                float os = __shfl_xor(bs[ms][r], off, 64);
                int ok = __shfl_xor(bkr[ms][r], off, 64);
                if (os < bs[ms][r] || (os == bs[ms][r] && ok < bkr[ms][r])) {
                    bs[ms][r] = os; bkr[ms][r] = ok;
                }
            }
    }
    if (lr == 0) {
        #pragma unroll
        for (int ms = 0; ms < 4; ++ms)
            #pragma unroll
            for (int r = 0; r < 4; ++r) {
                int row = ms * 16 + lk * 4 + r;
                red_s[wv * 64 + row] = bs[ms][r];
                red_k[wv * 64 + row] = bkr[ms][r];
            }
    }
    __syncthreads();
    if (tid < 64) {
        float s0 = red_s[tid]; int k0 = red_k[tid];
        #pragma unroll
        for (int v = 1; v < 4; ++v) {   // ascending wave = ascending code range -> first-min
            float s = red_s[v * 64 + tid]; int k = red_k[v * 64 + tid];
            if (s < s0 || (s == s0 && k < k0)) { s0 = s; k0 = k; }
        }
        bk_sh[tid] = k0;
    }
    __syncthreads();

    // epilogue: loss (fp32 enc) + quant scatter; per-block partial (no atomics)
    int bcode = bk_sh[cl];
    const float* ev = emb + bcode * 64;
    unsigned short* qd = qdec + b * 262144 + w * 64 + cl;
    float ls = 0.f;
    #pragma unroll
    for (int hp = 0; hp < 16; ++hp) {
        int h = hp * 4 + hg;
        float e = ev[h];
        float f = encb[h * 4096 + cl];
        float d = e - f;
        ls += d * d;
        qd[h * 4096] = f2b(e);
    }
    #pragma unroll
    for (int off = 32; off; off >>= 1) ls += __shfl_xor(ls, off, 64);
    if (lane == 0) wls[wv] = ls;
    __syncthreads();
    if (tid == 0) lossp[rb] = (wls[0] + wls[1]) + (wls[2] + wls[3]);
}

// ---------------------------------------------------------------- loss finalize: sum 1024 partials -> loss[0]
__global__ __launch_bounds__(256) void k_losssum(const float* __restrict__ lossp, float* __restrict__ loss) {
    __shared__ float wsum[4];
    int tid = threadIdx.x;
    float s = lossp[tid] + lossp[tid + 256] + lossp[tid + 512] + lossp[tid + 768];
    #pragma unroll
    for (int off = 32; off; off >>= 1) s += __shfl_xor(s, off, 64);
    if ((tid & 63) == 0) wsum[tid >> 6] = s;
    __syncthreads();
    if (tid == 0) loss[0] = (wsum[0] + wsum[1]) + (wsum[2] + wsum[3]);
}

// ---------------------------------------------------------------- deconv1 MFMA: qdec bf16 -> g bf16[16,128,128,256]
__global__ __launch_bounds__(256) void k_deconv1(const unsigned short* __restrict__ qdec,
                                                 const unsigned short* __restrict__ dw1p,
                                                 const float* __restrict__ db1, unsigned short* __restrict__ g) {
    int bx = blockIdx.x;
    int parx = bx & 1, y = (bx >> 1) & 127, b = bx >> 8;
    int pary = y & 1;
    int h0 = (y - 2 + pary) >> 1;
    int tid = threadIdx.x;
    int wv = tid >> 6, lane = tid & 63;
    int lr = lane & 15, lk = lane >> 4;
    f32x4 acc[4][4];
    #pragma unroll
    for (int i = 0; i < 4; ++i)
        #pragma unroll
        for (int j = 0; j < 4; ++j) acc[i][j] = (f32x4){0.f, 0.f, 0.f, 0.f};

    const unsigned short* qb = qdec + (size_t)b * (64 * 64 * 64);
    #pragma unroll
    for (int tky = 0; tky < 2; ++tky) {
        int h = h0 + tky;
        bool hok = (unsigned)h < 64u;
        const unsigned short* rowp = qb + h * (64 * 64);
        #pragma unroll
        for (int tkx = 0; tkx < 2; ++tkx) {
            int tap = (pary + 2 * tky) * 4 + parx + 2 * tkx;
            int wbase = lr + parx + tkx - 1;
            #pragma unroll
            for (int cc = 0; cc < 2; ++cc) {
                int c0 = cc * 32 + lk * 8;
                s16x8 aF[4];
                #pragma unroll
                for (int ms = 0; ms < 4; ++ms) {
                    int w = wbase + ms * 16;
                    aF[ms] = ldz(rowp + w * 64 + c0, hok && (unsigned)w < 64u);
                }
                const unsigned short* wp = dw1p + (((tap * 2 + cc) * 16 + wv * 4) * 64 + lane) * 8;
                s16x8 bF[4];
                #pragma unroll
                for (int ns = 0; ns < 4; ++ns) bF[ns] = *(const s16x8*)(wp + ns * 512);
                #pragma unroll
                for (int ms = 0; ms < 4; ++ms)
                    #pragma unroll
                    for (int ns = 0; ns < 4; ++ns)
                        acc[ms][ns] = __builtin_amdgcn_mfma_f32_16x16x32_bf16(aF[ms], bF[ns], acc[ms][ns], 0, 0, 0);
            }
        }
    }
    int ocb = wv * 64;
    unsigned short* gp = g + ((size_t)(b * 128 + y)) * 128 * 256;
    #pragma unroll
    for (int ns = 0; ns < 4; ++ns) {
        float bb = db1[ocb + ns * 16 + lr];
        #pragma unroll
        for (int ms = 0; ms < 4; ++ms)
            #pragma unroll
            for (int r = 0; r < 4; ++r) {
                int u = ms * 16 + lk * 4 + r;
                int xo = 2 * u + parx;
                gp[xo * 256 + ocb + ns * 16 + lr] = f2b(leaky(acc[ms][ns][r] + bb));
            }
    }
}

// ---------------------------------------------------------------- deconv2 MFMA, LDS-staged: g bf16 -> recon fp32, tanh
__global__ __launch_bounds__(256) void k_deconv2(const unsigned short* __restrict__ g,
                                                 const unsigned short* __restrict__ dwp,
                                                 const float* __restrict__ db2, float* __restrict__ out,
                                                 const float* __restrict__ loss) {
    __shared__ unsigned short gs[2][128][128];
    int bx = blockIdx.x;
    int swz = (bx % 8) * 258 + bx / 8;        // 2064 blocks; XCD-chunked
    int b = swz / 129, m = swz % 129;
    int tid = threadIdx.x;
    int wv = tid >> 6, lane = tid & 63;
    int lr = lane & 15, lk = lane >> 4;
    int yi = wv >> 1, px0 = wv & 1;
    int y = 2 * m - 1 + yi;
    int py = yi ^ 1;

    f32x4 acc[8];
    #pragma unroll
    for (int i = 0; i < 8; ++i) acc[i] = (f32x4){0.f, 0.f, 0.f, 0.f};

    const unsigned short* gb = g + (size_t)b * (128 * 128 * 256);
    const unsigned short* dwb = dwp + (size_t)(py * 2 + px0) * 32 * 512;

    #pragma unroll 1
    for (int cc = 0; cc < 2; ++cc) {
        __syncthreads();
        #pragma unroll
        for (int i = 0; i < 16; ++i) {
            int ch = i * 256 + tid;             // 0..4095
            int cg = ch & 15;
            int w  = (ch >> 4) & 127;
            int tky = ch >> 11;
            int h = m - 1 + tky;
            s16x8 v = {0,0,0,0,0,0,0,0};
            if ((unsigned)h < 128u)
                v = *(const s16x8*)(gb + h * (128 * 256) + w * 256 + cc * 128 + cg * 8);
            *(s16x8*)(&gs[tky][w][(cg ^ (w & 15)) << 3]) = v;
        }
        __syncthreads();
        #pragma unroll
        for (int tky = 0; tky < 2; ++tky) {
            #pragma unroll
            for (int tkx = 0; tkx < 2; ++tkx) {
                int tap = tky * 2 + tkx;
                int wofs = px0 - 1 + tkx;
                #pragma unroll
                for (int k8 = 0; k8 < 4; ++k8) {
                    int ks = tap * 8 + cc * 4 + k8;
                    s16x8 bF = *(const s16x8*)(dwb + (ks * 64 + lane) * 8);
                    int cg = k8 * 4 + lk;
                    #pragma unroll
                    for (int ms = 0; ms < 8; ++ms) {
                        int w = ms * 16 + lr + wofs;
                        s16x8 aF = {0,0,0,0,0,0,0,0};
                        if ((unsigned)w < 128u)
                            aF = *(const s16x8*)(&gs[tky][w][(cg ^ (w & 15)) << 3]);
                        acc[ms] = __builtin_amdgcn_mfma_f32_16x16x32_bf16(aF, bF, acc[ms], 0, 0, 0);
                    }
                }
            }
        }
    }
    if ((unsigned)y < 256u && lr < 3) {
        float bb = db2[lr];
        #pragma unroll
        for (int ms = 0; ms < 8; ++ms)
            #pragma unroll
            for (int r = 0; r < 4; ++r) {
                int n = ms * 16 + lk * 4 + r;
                int x = 2 * n + px0;
                out[((size_t)b * 65536 + y * 256 + x) * 3 + lr] = tanhf(acc[ms][r] + bb);
            }
    }
    if (bx == 0 && tid == 0)
        out[3145728] = loss[0] * (1.25f / 4194304.f);
}

// ---------------------------------------------------------------- launch
extern "C" void kernel_launch(void* const* d_in, const int* in_sizes, int n_in,
                              void* d_out, int out_size, void* d_ws, size_t ws_size,
                              hipStream_t stream) {
    const float* x   = (const float*)d_in[0];
    const float* emb = (const float*)d_in[1];
    const float* w1  = (const float*)d_in[2];
    const float* b1  = (const float*)d_in[3];
    const float* w2  = (const float*)d_in[4];
    const float* b2  = (const float*)d_in[5];
    const float* w3  = (const float*)d_in[6];
    const float* b3  = (const float*)d_in[7];
    const float* dw1 = (const float*)d_in[8];
    const float* db1 = (const float*)d_in[9];
    const float* dw2 = (const float*)d_in[10];
    const float* db2 = (const float*)d_in[11];
    float* out = (float*)d_out;
    float* ws  = (float*)d_ws;

    if (ws_size < (size_t)40348688 * 4) return;

    unsigned short* h1b  = (unsigned short*)ws;            // bf16, later overlapped by g
    unsigned short* g    = (unsigned short*)ws;            // bf16 [16,128,128,256]
    float* enc   = ws + 33554432;
    unsigned short* qdec = (unsigned short*)(ws + 37748736);
    float* enorm = ws + 39845888;
    float* loss  = ws + 39847936;
    unsigned short* w2p  = (unsigned short*)(ws + 39847952);
    unsigned short* dw1p = (unsigned short*)(ws + 40110096);
    unsigned short* w3p  = (unsigned short*)(ws + 40241168);
    unsigned short* dwp  = (unsigned short*)(ws + 40249360);
    unsigned short* ebp  = (unsigned short*)(ws + 40282128);
    float* lossp = ws + 40347664;

    k_prep   <<<8,     256, 0, stream>>>(emb, enorm, loss, ebp);
    k_pack   <<<3392,  256, 0, stream>>>(w2, dw1, w3, dw2, w2p, dw1p, w3p, dwp);
    k_conv1  <<<65536, 128, 0, stream>>>(x, w1, b1, h1b);
    k_conv2  <<<1024,  256, 0, stream>>>(h1b, w2p, b2, w3p, b3, enc);
    k_vq     <<<1024,  256, 0, stream>>>(enc, ebp, emb, enorm, qdec, lossp);
    k_losssum<<<1,     256, 0, stream>>>(lossp, loss);
    k_deconv1<<<4096,  256, 0, stream>>>(qdec, dw1p, db1, g);
    k_deconv2<<<2064,  256, 0, stream>>>(g, dwp, db2, out, loss);
}